// Round 16
// baseline (171.434 us; speedup 1.0000x reference)
//
#include <hip/hip_runtime.h>

#define DIM    64
#define NEMB   1024
#define HW     4096      // 64*64
#define NPIX   131072    // 32*64*64
#define NOUT   8388608   // 32*64*64*64
#define PIXBLK 128       // pixels per screen block
#define NTILE  64        // 1024/16 code tiles
#define TPW    16        // tiles per wave (4 waves cover 64)
#define MARGIN 2.0f      // >= 5x worst-case screen error (split ~0.2 + f16 ~0.25, x2)

using short8 = __attribute__((ext_vector_type(8))) short;
using f32x4  = __attribute__((ext_vector_type(4))) float;

#define MFMA(A, B, C) __builtin_amdgcn_mfma_f32_16x16x32_bf16((A), (B), (C), 0, 0, 0)

__device__ __forceinline__ unsigned short bf16_rne(float f) {
    unsigned u = __float_as_uint(f);
    return (unsigned short)((u + 0x7fffu + ((u >> 16) & 1u)) >> 16);
}

// ---------------------------------------------------------------------------
// prep1: cn[j] = ||e_j||^2 (numpy axis-0 order: sequential adds of rounded muls)
// ---------------------------------------------------------------------------
__global__ __launch_bounds__(256) void prep1(const float* __restrict__ embed,
                                             float* __restrict__ cn) {
    const int j = blockIdx.x * 256 + threadIdx.x;
    if (j >= NEMB) return;
    float v = embed[j];
    float s = __fmul_rn(v, v);
#pragma unroll
    for (int d = 1; d < DIM; ++d) {
        v = embed[d * NEMB + j];
        s = __fadd_rn(s, __fmul_rn(v, v));
    }
    cn[j] = s;
}

// ---------------------------------------------------------------------------
// prep2: split -2*embed into bf16 hi/lo in MFMA A-fragment order (== R9-R14,
// verified by absmax=0): flat = ((ct*2+kc)*64 + (g*16+r))*8 + i,
// d = kc*32+g*8+i, code = ct*16+r.
// ---------------------------------------------------------------------------
__global__ __launch_bounds__(256) void prep2(const float* __restrict__ embed,
                                             unsigned short* __restrict__ ehi,
                                             unsigned short* __restrict__ elo) {
    const int gid = blockIdx.x * 256 + threadIdx.x;   // 64*1024 elements
    const int d = gid >> 10;
    const int j = gid & 1023;
    const float es = -2.0f * embed[d * NEMB + j];
    const unsigned short h = bf16_rne(es);
    const float hv = __uint_as_float((unsigned)h << 16);
    const unsigned short lo = bf16_rne(es - hv);
    const int ct = j >> 4, r = j & 15;
    const int kc = d >> 5, g = (d >> 3) & 3, i = d & 7;
    const int idx = ((ct * 2 + kc) * 64 + (g * 16 + r)) * 8 + i;
    ehi[idx] = h;
    elo[idx] = lo;
}

// ---------------------------------------------------------------------------
// prep3: cn in C-fragment order (== R9-R14): lane l, reg q -> ct*16+(l>>4)*4+q
// ---------------------------------------------------------------------------
__global__ __launch_bounds__(256) void prep3(const float* __restrict__ cn,
                                             float* __restrict__ cnfrag) {
    const int t = blockIdx.x * 256 + threadIdx.x;     // 64*64*4
    const int q = t & 3, l = (t >> 2) & 63, ct = t >> 8;
    cnfrag[t] = cn[ct * 16 + (l >> 4) * 4 + q];
}

// ---------------------------------------------------------------------------
// Kernel A — screen (unchanged from R14): stage x as bf16, MFMA screen,
// per-pixel enumerate -> u64 candidate-tile MASK to global.
// ---------------------------------------------------------------------------
__global__ __launch_bounds__(256)
__attribute__((amdgpu_waves_per_eu(4, 4)))
void screen_kernel(const float* __restrict__ X,
                   const float* __restrict__ cnfrag,
                   const unsigned short* __restrict__ ehi,
                   const unsigned short* __restrict__ elo,
                   unsigned long long* __restrict__ mask_g) {
    __shared__ unsigned short xbf[DIM][PIXBLK + 2];  // 16.6 KB
    __shared__ _Float16 tm_lds[NTILE][PIXBLK];       // 16 KB

    const int tid  = threadIdx.x;
    const int l    = tid & 63;
    const int w    = tid >> 6;
    const int pix0 = blockIdx.x * PIXBLK;
    const int b    = pix0 >> 12;
    const int p0   = pix0 & 4095;

    // ---- 0. hoisted prefetch of tile ct0 = w*TPW (w-only dependence)
    const int ct0 = w * TPW;
    f32x4  cnc = *(const f32x4*)(cnfrag + (ct0 * 64 + l) * 4);
    short8 eh0 = *(const short8*)(ehi + ((ct0 * 2 + 0) * 64 + l) * 8);
    short8 eh1 = *(const short8*)(ehi + ((ct0 * 2 + 1) * 64 + l) * 8);
    short8 el0 = *(const short8*)(elo + ((ct0 * 2 + 0) * 64 + l) * 8);
    short8 el1 = *(const short8*)(elo + ((ct0 * 2 + 1) * 64 + l) * 8);

    // ---- 1. stage as bf16 (same bf16_rne values as the R13 fragment build)
    {
        const int sp = tid & (PIXBLK - 1);
        const int dh = tid >> 7;
        const float* xb = X + (size_t)b * (DIM * HW) + p0 + sp;
#pragma unroll
        for (int k = 0; k < DIM / 2; ++k) {
            const int d = dh * (DIM / 2) + k;
            xbf[d][sp] = bf16_rne(xb[(size_t)d * HW]);
        }
    }
    __syncthreads();

    // ---- 2. x B-fragments for all 8 subtiles from bf16 LDS
    const int g  = l >> 4;
    const int lr = l & 15;
    short8 xh[8][2];     // 64 VGPR
#pragma unroll
    for (int s = 0; s < 8; ++s)
#pragma unroll
        for (int kc = 0; kc < 2; ++kc)
#pragma unroll
            for (int i = 0; i < 8; ++i) {
                const int d = kc * 32 + g * 8 + i;
                xh[s][kc][i] = (short)xbf[d][s * 16 + lr];
            }

    // ---- 3. screen: wave w owns tiles [16w,16w+16), 1-deep prefetch
#pragma unroll 1
    for (int t = 0; t < TPW; ++t) {
        const int ct = ct0 + t;
        f32x4 cnn = cnc;
        short8 eh0n = eh0, eh1n = eh1, el0n = el0, el1n = el1;
        if (t + 1 < TPW) {
            const int c2 = (ct + 1) * 2;
            cnn  = *(const f32x4*)(cnfrag + ((ct + 1) * 64 + l) * 4);
            eh0n = *(const short8*)(ehi + ((c2 + 0) * 64 + l) * 8);
            eh1n = *(const short8*)(ehi + ((c2 + 1) * 64 + l) * 8);
            el0n = *(const short8*)(elo + ((c2 + 0) * 64 + l) * 8);
            el1n = *(const short8*)(elo + ((c2 + 1) * 64 + l) * 8);
        }
#pragma unroll
        for (int s = 0; s < 8; ++s) {
            f32x4 c0 = cnc, c1 = {0.f, 0.f, 0.f, 0.f};
            c0 = MFMA(el0, xh[s][0], c0);
            c1 = MFMA(el1, xh[s][1], c1);
            c0 = MFMA(eh0, xh[s][0], c0);
            c1 = MFMA(eh1, xh[s][1], c1);
            float m = fminf(fminf(c0[0] + c1[0], c0[1] + c1[1]),
                            fminf(c0[2] + c1[2], c0[3] + c1[3]));
            m = fminf(m, __shfl_xor(m, 16, 64));
            m = fminf(m, __shfl_xor(m, 32, 64));
            if (l < 16) tm_lds[ct][s * 16 + l] = (_Float16)m;
        }
        cnc = cnn; eh0 = eh0n; eh1 = eh1n; el0 = el0n; el1 = el1n;
    }
    __syncthreads();

    // ---- 4. enumerate: per pixel, min + threshold + candidate-tile mask
    if (tid < PIXBLK) {
        float m0 = (float)tm_lds[0][tid], m1 = (float)tm_lds[1][tid];
        float m2 = (float)tm_lds[2][tid], m3 = (float)tm_lds[3][tid];
#pragma unroll
        for (int ct = 4; ct < NTILE; ct += 4) {
            m0 = fminf(m0, (float)tm_lds[ct + 0][tid]);
            m1 = fminf(m1, (float)tm_lds[ct + 1][tid]);
            m2 = fminf(m2, (float)tm_lds[ct + 2][tid]);
            m3 = fminf(m3, (float)tm_lds[ct + 3][tid]);
        }
        const float thr = fminf(fminf(m0, m1), fminf(m2, m3)) + MARGIN;
        unsigned long long mk = 0;
#pragma unroll
        for (int ct = 0; ct < NTILE; ++ct)
            if ((float)tm_lds[ct][tid] <= thr) mk |= 1ull << ct;
        mask_g[pix0 + tid] = mk;
    }
}

// ---------------------------------------------------------------------------
// Kernel B — rescore + output. R14 lesson (same as R2-R5): without a
// waves-per-EU cap the backend targets 8 waves/EU (<=64 VGPR, observed 56)
// and destroys the 16-wide strips -> e-load latency exposed ~8-16x per entry
// -> 119us. amdgpu_waves_per_eu(4,4) restores the 128-VGPR pressure target;
// strips stay register-resident. All arithmetic bitwise == R14 (absmax 0).
// ---------------------------------------------------------------------------
__global__ __launch_bounds__(256)
__attribute__((amdgpu_waves_per_eu(4, 4)))
void finish_kernel(const float* __restrict__ X,
                   const float* __restrict__ embed,
                   const float* __restrict__ cn,
                   const unsigned long long* __restrict__ mask_g,
                   float* __restrict__ OUT,
                   float* __restrict__ loss) {
    __shared__ float xlds[DIM][16];                 // 4 KB
    __shared__ unsigned long long best[16];
    __shared__ float sred[256];

    const int tid  = threadIdx.x;
    const int grp  = tid >> 4;       // 16 groups = 16 pixels
    const int cc   = tid & 15;       // code lane within group
    const int pixb = blockIdx.x * 16;
    const int b    = pixb >> 12;
    const int p0   = pixb & 4095;

    // ---- stage 16 pixels x 64 d (64B-aligned segments)
    {
        const int sp = tid & 15;      // pixel
        const int dg = tid >> 4;      // d-group of 4
        const float* xb = X + (size_t)b * (DIM * HW) + p0 + sp;
#pragma unroll
        for (int k = 0; k < 4; ++k) {
            const int d = dg * 4 + k;
            xlds[d][sp] = xb[(size_t)d * HW];
        }
    }
    __syncthreads();

    // ---- per-group: ff (pairwise-8, redundant across lanes, bitwise == R0)
    float rr[8];
#pragma unroll
    for (int i = 0; i < 8; ++i) {
        const float v = xlds[i][grp];
        rr[i] = __fmul_rn(v, v);
    }
#pragma unroll
    for (int i = 8; i < DIM; i += 8)
#pragma unroll
        for (int q = 0; q < 8; ++q) {
            const float v = xlds[i + q][grp];
            rr[q] = __fadd_rn(rr[q], __fmul_rn(v, v));
        }
    const float ffv = __fadd_rn(
        __fadd_rn(__fadd_rn(rr[0], rr[1]), __fadd_rn(rr[2], rr[3])),
        __fadd_rn(__fadd_rn(rr[4], rr[5]), __fadd_rn(rr[6], rr[7])));

    // ---- walk candidate tiles; strip-mined exact rescore (== R13 chain)
    unsigned long long mk = mask_g[pixb + grp];   // group-uniform
    unsigned long long bb = 0xFFFFFFFFFFFFFFFFull;
#pragma unroll 1
    while (mk) {
        const int ct = (int)__builtin_ctzll(mk);
        mk &= mk - 1;
        const int j = ct * 16 + cc;
        float a = 0.f;
#pragma unroll
        for (int dc = 0; dc < 4; ++dc) {
            float ev[16], xv[16];
#pragma unroll
            for (int k = 0; k < 16; ++k)
                ev[k] = embed[(dc * 16 + k) * NEMB + j];   // 16 indep loads
#pragma unroll
            for (int k = 0; k < 16; ++k)
                xv[k] = xlds[dc * 16 + k][grp];
#pragma unroll
            for (int k = 0; k < 16; ++k)
                a = fmaf(xv[k], ev[k], a);                 // sequential-d == R0
        }
        const float dist = __fadd_rn(__fsub_rn(ffv, __fmul_rn(2.f, a)), cn[j]);
        const unsigned long long pk =
            ((unsigned long long)__float_as_uint(dist) << 32) | (unsigned)j;
        bb = pk < bb ? pk : bb;   // u64 min: exact, ties -> smaller j
    }
    // group reduce (xor 1,2,4,8 stays within the 16-lane group)
#pragma unroll
    for (int m = 1; m < 16; m <<= 1) {
        const unsigned long long o = __shfl_xor(bb, m, 64);
        bb = o < bb ? o : bb;
    }
    if (cc == 0) best[grp] = bb;
    __syncthreads();

    // ---- output + loss: thread t -> pixel t&15, d-group t>>4 (64B segments)
    const int sp  = tid & 15;
    const int dg  = tid >> 4;
    const int idx = (int)(best[sp] & 0xFFFFFFFFull);
    float lerr = 0.f;
    float* outb = OUT + (size_t)b * (DIM * HW) + p0 + sp;
#pragma unroll
    for (int k = 0; k < 4; ++k) {
        const int d = dg * 4 + k;
        const float qv = embed[d * NEMB + idx];
        const float xv = xlds[d][sp];
        const float df = __fsub_rn(qv, xv);
        outb[(size_t)d * HW] = __fadd_rn(xv, df);
        lerr = fmaf(df, df, lerr);
    }

    sred[tid] = lerr;
    __syncthreads();
#pragma unroll
    for (int s = 128; s > 0; s >>= 1) {
        if (tid < s) sred[tid] += sred[tid + s];
        __syncthreads();
    }
    if (tid == 0)
        atomicAdd(loss, sred[0] * (1.0f / (float)NOUT));
}

extern "C" void kernel_launch(void* const* d_in, const int* in_sizes, int n_in,
                              void* d_out, int out_size, void* d_ws, size_t ws_size,
                              hipStream_t stream) {
    const float* X = (const float*)d_in[0];
    const float* E = (const float*)d_in[1];
    float* OUT  = (float*)d_out;
    float* loss = OUT + NOUT;

    // ws layout (bytes): cn 4K | cnfrag 64K | ehi 128K | elo 128K | mask 1M
    char* wsb = (char*)d_ws;
    float* cn                 = (float*)(wsb);
    float* cnfrag             = (float*)(wsb + 4096);
    unsigned short* ehi       = (unsigned short*)(wsb + 4096 + 65536);
    unsigned short* elo       = (unsigned short*)(wsb + 4096 + 65536 + 131072);
    unsigned long long* maskg = (unsigned long long*)(wsb + 4096 + 65536 + 262144);

    hipMemsetAsync(loss, 0, sizeof(float), stream);
    prep1<<<NEMB / 256, 256, 0, stream>>>(E, cn);
    prep2<<<(DIM * NEMB) / 256, 256, 0, stream>>>(E, ehi, elo);
    prep3<<<(NTILE * 64 * 4) / 256, 256, 0, stream>>>(cn, cnfrag);
    screen_kernel<<<NPIX / PIXBLK, 256, 0, stream>>>(X, cnfrag, ehi, elo, maskg);
    finish_kernel<<<NPIX / 16, 256, 0, stream>>>(X, E, cn, maskg, OUT, loss);
}

// Round 17
// 124.272 us; speedup vs baseline: 1.3795x; 1.3795x over previous
//
#include <hip/hip_runtime.h>

#define DIM    64
#define NEMB   1024
#define HW     4096      // 64*64
#define NPIX   131072    // 32*64*64
#define NOUT   8388608   // 32*64*64*64
#define PIXBLK 128       // pixels per screen/finish block
#define NTILE  64        // 1024/16 code tiles
#define TPW    16        // tiles per wave (4 waves cover 64)
#define MARGIN 2.0f      // >= 5x worst-case screen error (split ~0.2 + f16 ~0.25, x2)

using short8 = __attribute__((ext_vector_type(8))) short;
using f32x4  = __attribute__((ext_vector_type(4))) float;

#define MFMA(A, B, C) __builtin_amdgcn_mfma_f32_16x16x32_bf16((A), (B), (C), 0, 0, 0)

__device__ __forceinline__ unsigned short bf16_rne(float f) {
    unsigned u = __float_as_uint(f);
    return (unsigned short)((u + 0x7fffu + ((u >> 16) & 1u)) >> 16);
}

// ---------------------------------------------------------------------------
// prep1: cn[j] = ||e_j||^2 (numpy axis-0 order: sequential adds of rounded muls)
// ---------------------------------------------------------------------------
__global__ __launch_bounds__(256) void prep1(const float* __restrict__ embed,
                                             float* __restrict__ cn) {
    const int j = blockIdx.x * 256 + threadIdx.x;
    if (j >= NEMB) return;
    float v = embed[j];
    float s = __fmul_rn(v, v);
#pragma unroll
    for (int d = 1; d < DIM; ++d) {
        v = embed[d * NEMB + j];
        s = __fadd_rn(s, __fmul_rn(v, v));
    }
    cn[j] = s;
}

// ---------------------------------------------------------------------------
// prep2: split -2*embed into bf16 hi/lo in MFMA A-fragment order (== R9-R15,
// verified by absmax=0): flat = ((ct*2+kc)*64 + (g*16+r))*8 + i,
// d = kc*32+g*8+i, code = ct*16+r.
// ---------------------------------------------------------------------------
__global__ __launch_bounds__(256) void prep2(const float* __restrict__ embed,
                                             unsigned short* __restrict__ ehi,
                                             unsigned short* __restrict__ elo) {
    const int gid = blockIdx.x * 256 + threadIdx.x;   // 64*1024 elements
    const int d = gid >> 10;
    const int j = gid & 1023;
    const float es = -2.0f * embed[d * NEMB + j];
    const unsigned short h = bf16_rne(es);
    const float hv = __uint_as_float((unsigned)h << 16);
    const unsigned short lo = bf16_rne(es - hv);
    const int ct = j >> 4, r = j & 15;
    const int kc = d >> 5, g = (d >> 3) & 3, i = d & 7;
    const int idx = ((ct * 2 + kc) * 64 + (g * 16 + r)) * 8 + i;
    ehi[idx] = h;
    elo[idx] = lo;
}

// ---------------------------------------------------------------------------
// prep3: cn in C-fragment order (== R9-R15): lane l, reg q -> ct*16+(l>>4)*4+q
// ---------------------------------------------------------------------------
__global__ __launch_bounds__(256) void prep3(const float* __restrict__ cn,
                                             float* __restrict__ cnfrag) {
    const int t = blockIdx.x * 256 + threadIdx.x;     // 64*64*4
    const int q = t & 3, l = (t >> 2) & 63, ct = t >> 8;
    cnfrag[t] = cn[ct * 16 + (l >> 4) * 4 + q];
}

// ---------------------------------------------------------------------------
// Kernel A — screen (unchanged from R14/R15): stage x as bf16, MFMA screen,
// per-pixel enumerate -> u64 candidate-tile MASK to global.
// ---------------------------------------------------------------------------
__global__ __launch_bounds__(256)
__attribute__((amdgpu_waves_per_eu(4, 4)))
void screen_kernel(const float* __restrict__ X,
                   const float* __restrict__ cnfrag,
                   const unsigned short* __restrict__ ehi,
                   const unsigned short* __restrict__ elo,
                   unsigned long long* __restrict__ mask_g) {
    __shared__ unsigned short xbf[DIM][PIXBLK + 2];  // 16.6 KB
    __shared__ _Float16 tm_lds[NTILE][PIXBLK];       // 16 KB

    const int tid  = threadIdx.x;
    const int l    = tid & 63;
    const int w    = tid >> 6;
    const int pix0 = blockIdx.x * PIXBLK;
    const int b    = pix0 >> 12;
    const int p0   = pix0 & 4095;

    // ---- 0. hoisted prefetch of tile ct0 = w*TPW (w-only dependence)
    const int ct0 = w * TPW;
    f32x4  cnc = *(const f32x4*)(cnfrag + (ct0 * 64 + l) * 4);
    short8 eh0 = *(const short8*)(ehi + ((ct0 * 2 + 0) * 64 + l) * 8);
    short8 eh1 = *(const short8*)(ehi + ((ct0 * 2 + 1) * 64 + l) * 8);
    short8 el0 = *(const short8*)(elo + ((ct0 * 2 + 0) * 64 + l) * 8);
    short8 el1 = *(const short8*)(elo + ((ct0 * 2 + 1) * 64 + l) * 8);

    // ---- 1. stage as bf16 (same bf16_rne values as the R13 fragment build)
    {
        const int sp = tid & (PIXBLK - 1);
        const int dh = tid >> 7;
        const float* xb = X + (size_t)b * (DIM * HW) + p0 + sp;
#pragma unroll
        for (int k = 0; k < DIM / 2; ++k) {
            const int d = dh * (DIM / 2) + k;
            xbf[d][sp] = bf16_rne(xb[(size_t)d * HW]);
        }
    }
    __syncthreads();

    // ---- 2. x B-fragments for all 8 subtiles from bf16 LDS
    const int g  = l >> 4;
    const int lr = l & 15;
    short8 xh[8][2];     // 64 VGPR
#pragma unroll
    for (int s = 0; s < 8; ++s)
#pragma unroll
        for (int kc = 0; kc < 2; ++kc)
#pragma unroll
            for (int i = 0; i < 8; ++i) {
                const int d = kc * 32 + g * 8 + i;
                xh[s][kc][i] = (short)xbf[d][s * 16 + lr];
            }

    // ---- 3. screen: wave w owns tiles [16w,16w+16), 1-deep prefetch
#pragma unroll 1
    for (int t = 0; t < TPW; ++t) {
        const int ct = ct0 + t;
        f32x4 cnn = cnc;
        short8 eh0n = eh0, eh1n = eh1, el0n = el0, el1n = el1;
        if (t + 1 < TPW) {
            const int c2 = (ct + 1) * 2;
            cnn  = *(const f32x4*)(cnfrag + ((ct + 1) * 64 + l) * 4);
            eh0n = *(const short8*)(ehi + ((c2 + 0) * 64 + l) * 8);
            eh1n = *(const short8*)(ehi + ((c2 + 1) * 64 + l) * 8);
            el0n = *(const short8*)(elo + ((c2 + 0) * 64 + l) * 8);
            el1n = *(const short8*)(elo + ((c2 + 1) * 64 + l) * 8);
        }
#pragma unroll
        for (int s = 0; s < 8; ++s) {
            f32x4 c0 = cnc, c1 = {0.f, 0.f, 0.f, 0.f};
            c0 = MFMA(el0, xh[s][0], c0);
            c1 = MFMA(el1, xh[s][1], c1);
            c0 = MFMA(eh0, xh[s][0], c0);
            c1 = MFMA(eh1, xh[s][1], c1);
            float m = fminf(fminf(c0[0] + c1[0], c0[1] + c1[1]),
                            fminf(c0[2] + c1[2], c0[3] + c1[3]));
            m = fminf(m, __shfl_xor(m, 16, 64));
            m = fminf(m, __shfl_xor(m, 32, 64));
            if (l < 16) tm_lds[ct][s * 16 + l] = (_Float16)m;
        }
        cnc = cnn; eh0 = eh0n; eh1 = eh1n; el0 = el0n; el1 = el1n;
    }
    __syncthreads();

    // ---- 4. enumerate: per pixel, min + threshold + candidate-tile mask
    if (tid < PIXBLK) {
        float m0 = (float)tm_lds[0][tid], m1 = (float)tm_lds[1][tid];
        float m2 = (float)tm_lds[2][tid], m3 = (float)tm_lds[3][tid];
#pragma unroll
        for (int ct = 4; ct < NTILE; ct += 4) {
            m0 = fminf(m0, (float)tm_lds[ct + 0][tid]);
            m1 = fminf(m1, (float)tm_lds[ct + 1][tid]);
            m2 = fminf(m2, (float)tm_lds[ct + 2][tid]);
            m3 = fminf(m3, (float)tm_lds[ct + 3][tid]);
        }
        const float thr = fminf(fminf(m0, m1), fminf(m2, m3)) + MARGIN;
        unsigned long long mk = 0;
#pragma unroll
        for (int ct = 0; ct < NTILE; ++ct)
            if ((float)tm_lds[ct][tid] <= thr) mk |= 1ull << ct;
        mask_g[pix0 + tid] = mk;
    }
}

// ---------------------------------------------------------------------------
// Kernel B — rescore + output, R16: 128 pixels/block (1024 blocks).
// R15 lesson: the 16-pixel micro-blocks were the cost — unamortized stage
// latency (64B segments), 10+ barriers per tiny block, and 8192 contended
// same-address atomicAdds. Now: 512B-coalesced stage into 32KB LDS (bitwise
// R13 stage), each 16-lane group EXCLUSIVELY owns 8 pixels (no LDS atomics,
// lane 0 writes best[pix] directly), strip-mined rescore chain (bitwise R0
// distances), per-block loss partial to ws (no global atomic; summed by a
// tiny reduce kernel).
// ---------------------------------------------------------------------------
__global__ __launch_bounds__(256)
__attribute__((amdgpu_waves_per_eu(3, 4)))
void finish_kernel(const float* __restrict__ X,
                   const float* __restrict__ embed,
                   const float* __restrict__ cn,
                   const unsigned long long* __restrict__ mask_g,
                   float* __restrict__ OUT,
                   float* __restrict__ part) {
    __shared__ float xlds[DIM][PIXBLK];             // 32 KB
    __shared__ float ff_lds[PIXBLK];                // 512 B
    __shared__ unsigned long long best[PIXBLK];     // 1 KB
    __shared__ float sred[256];                     // 1 KB

    const int tid  = threadIdx.x;
    const int grp  = tid >> 4;       // 16 groups; group owns pixels grp+16t
    const int cc   = tid & 15;       // code lane within group
    const int pix0 = blockIdx.x * PIXBLK;
    const int b    = pix0 >> 12;
    const int p0   = pix0 & 4095;

    // ---- stage: all 256 threads, 2 per pixel (512B-coalesced rows, == R13)
    {
        const int sp = tid & (PIXBLK - 1);
        const int dh = tid >> 7;
        const float* xb = X + (size_t)b * (DIM * HW) + p0 + sp;
#pragma unroll
        for (int k = 0; k < DIM / 2; ++k) {
            const int d = dh * (DIM / 2) + k;
            xlds[d][sp] = xb[(size_t)d * HW];
        }
    }
    __syncthreads();

    // ---- ff per pixel (pairwise-8, bitwise == R0), threads 0..127
    if (tid < PIXBLK) {
        float rr[8];
#pragma unroll
        for (int i = 0; i < 8; ++i) {
            const float v = xlds[i][tid];
            rr[i] = __fmul_rn(v, v);
        }
#pragma unroll
        for (int i = 8; i < DIM; i += 8)
#pragma unroll
            for (int q = 0; q < 8; ++q) {
                const float v = xlds[i + q][tid];
                rr[q] = __fadd_rn(rr[q], __fmul_rn(v, v));
            }
        ff_lds[tid] = __fadd_rn(
            __fadd_rn(__fadd_rn(rr[0], rr[1]), __fadd_rn(rr[2], rr[3])),
            __fadd_rn(__fadd_rn(rr[4], rr[5]), __fadd_rn(rr[6], rr[7])));
    }
    __syncthreads();

    // ---- rescore: group grp owns pixels {grp + 16t}; walks each mask,
    //      strip-mined exact chain (sequential-d fmaf == R0, bitwise),
    //      packed-u64 lane-reduce; lane 0 writes best[pix] (exclusive owner).
#pragma unroll 1
    for (int t = 0; t < PIXBLK / 16; ++t) {
        const int pix = t * 16 + grp;
        const float ffv = ff_lds[pix];
        unsigned long long mk = mask_g[pix0 + pix];   // group-uniform
        unsigned long long bb = 0xFFFFFFFFFFFFFFFFull;
#pragma unroll 1
        while (mk) {
            const int ct = (int)__builtin_ctzll(mk);
            mk &= mk - 1;
            const int j = ct * 16 + cc;
            float a = 0.f;
#pragma unroll
            for (int dc = 0; dc < 4; ++dc) {
                float ev[16], xv[16];
#pragma unroll
                for (int k = 0; k < 16; ++k)
                    ev[k] = embed[(dc * 16 + k) * NEMB + j];   // 16 indep loads
#pragma unroll
                for (int k = 0; k < 16; ++k)
                    xv[k] = xlds[dc * 16 + k][pix];            // broadcast reads
#pragma unroll
                for (int k = 0; k < 16; ++k)
                    a = fmaf(xv[k], ev[k], a);                 // sequential-d == R0
            }
            const float dist = __fadd_rn(__fsub_rn(ffv, __fmul_rn(2.f, a)), cn[j]);
            const unsigned long long pk =
                ((unsigned long long)__float_as_uint(dist) << 32) | (unsigned)j;
            bb = pk < bb ? pk : bb;   // u64 min: exact, ties -> smaller j
        }
#pragma unroll
        for (int m = 1; m < 16; m <<= 1) {
            const unsigned long long o = __shfl_xor(bb, m, 64);
            bb = o < bb ? o : bb;
        }
        if (cc == 0) best[pix] = bb;
    }
    __syncthreads();

    // ---- output + loss partial: thread t -> pixel t&127, d-half t>>7 (== R13)
    const int pixe = tid & (PIXBLK - 1);
    const int dh   = tid >> 7;
    const int idx  = (int)(best[pixe] & 0xFFFFFFFFull);
    float lerr = 0.f;
    float* outb = OUT + (size_t)b * (DIM * HW) + p0 + pixe;
#pragma unroll 8
    for (int k = 0; k < DIM / 2; ++k) {
        const int d = dh * (DIM / 2) + k;
        const float qv = embed[d * NEMB + idx];
        const float xv = xlds[d][pixe];
        const float df = __fsub_rn(qv, xv);
        outb[(size_t)d * HW] = __fadd_rn(xv, df);
        lerr = fmaf(df, df, lerr);
    }

    sred[tid] = lerr;
    __syncthreads();
#pragma unroll
    for (int s = 128; s > 0; s >>= 1) {
        if (tid < s) sred[tid] += sred[tid + s];
        __syncthreads();
    }
    if (tid == 0) part[blockIdx.x] = sred[0];     // no global atomic
}

// ---------------------------------------------------------------------------
// reduce: sum 1024 per-block partials -> loss (single block, deterministic)
// ---------------------------------------------------------------------------
__global__ __launch_bounds__(256) void reduce_kernel(const float* __restrict__ part,
                                                     float* __restrict__ loss) {
    __shared__ float s[256];
    const int tid = threadIdx.x;
    s[tid] = ((part[tid] + part[tid + 256]) + (part[tid + 512] + part[tid + 768]));
    __syncthreads();
#pragma unroll
    for (int k = 128; k > 0; k >>= 1) {
        if (tid < k) s[tid] += s[tid + k];
        __syncthreads();
    }
    if (tid == 0) loss[0] = s[0] * (1.0f / (float)NOUT);
}

extern "C" void kernel_launch(void* const* d_in, const int* in_sizes, int n_in,
                              void* d_out, int out_size, void* d_ws, size_t ws_size,
                              hipStream_t stream) {
    const float* X = (const float*)d_in[0];
    const float* E = (const float*)d_in[1];
    float* OUT  = (float*)d_out;
    float* loss = OUT + NOUT;

    // ws layout (bytes): cn 4K | cnfrag 64K | ehi 128K | elo 128K | mask 1M | part 4K
    char* wsb = (char*)d_ws;
    float* cn                 = (float*)(wsb);
    float* cnfrag             = (float*)(wsb + 4096);
    unsigned short* ehi       = (unsigned short*)(wsb + 4096 + 65536);
    unsigned short* elo       = (unsigned short*)(wsb + 4096 + 65536 + 131072);
    unsigned long long* maskg = (unsigned long long*)(wsb + 4096 + 65536 + 262144);
    float* part               = (float*)(wsb + 4096 + 65536 + 262144 + NPIX * 8);

    prep1<<<NEMB / 256, 256, 0, stream>>>(E, cn);
    prep2<<<(DIM * NEMB) / 256, 256, 0, stream>>>(E, ehi, elo);
    prep3<<<(NTILE * 64 * 4) / 256, 256, 0, stream>>>(cn, cnfrag);
    screen_kernel<<<NPIX / PIXBLK, 256, 0, stream>>>(X, cnfrag, ehi, elo, maskg);
    finish_kernel<<<NPIX / PIXBLK, 256, 0, stream>>>(X, E, cn, maskg, OUT, part);
    reduce_kernel<<<1, 256, 0, stream>>>(part, loss);
}